// Round 13
// baseline (409.374 us; speedup 1.0000x reference)
//
#include <hip/hip_runtime.h>

// Problem constants
constexpr int Bb   = 2;
constexpr int Nn   = 2048;
constexpr int Hh   = 8;
constexpr int Dd   = 64;
constexpr int Mm   = Bb * Nn;      // 4096 rows
constexpr int TQKV = 1536;         // 3 * H * D
constexpr int INNER = Hh * Dd;     // 512
constexpr int CH   = 64;           // chunk length
constexpr int NCH  = Nn / CH;      // 32 chunks per (b,h)
constexpr int CSZ  = Dd * Dd + Dd; // 4160 floats per chunk record (S + kc)
constexpr float EPSF = 1e-7f;

typedef _Float16 half8 __attribute__((ext_vector_type(8)));
typedef _Float16 half4 __attribute__((ext_vector_type(4)));
typedef float f32x4 __attribute__((ext_vector_type(4)));

#define AS1(p) ((const __attribute__((address_space(1))) unsigned int*)(p))
#define AS3(p) ((__attribute__((address_space(3))) unsigned int*)(p))

// ---------------------------------------------------------------------------
// GEMM1-qk (fp32 VALU): R0-EXACT (71.9 us proven floor). q,k MUST stay
// fp32-VALU (R11-R14: MFMA split fails, denominator amplification).
// ---------------------------------------------------------------------------
__global__ __launch_bounds__(256) void gemm1_f32(
    const float* __restrict__ A, const float* __restrict__ B,
    float* __restrict__ C) {
  __shared__ float As[32][132];  // [k][m]
  __shared__ float Bs[32][68];   // [k][n]
  const int tid = threadIdx.x;
  const int tx = tid & 15, ty = tid >> 4;
  const int bm = blockIdx.y * 128, bn = blockIdx.x * 64;
  const int rowA = tid & 127, c4a = tid >> 7;  // 0..1
  const int rowB = tid & 63,  c4b = tid >> 6;  // 0..3

  float acc[8][4] = {};

  for (int k0 = 0; k0 < 512; k0 += 32) {
#pragma unroll
    for (int p = 0; p < 4; ++p) {
      int c4 = c4a + 2 * p;
      float4 fa = *(const float4*)(A + (size_t)(bm + rowA) * 512 + k0 + c4 * 4);
      As[c4 * 4 + 0][rowA] = fa.x; As[c4 * 4 + 1][rowA] = fa.y;
      As[c4 * 4 + 2][rowA] = fa.z; As[c4 * 4 + 3][rowA] = fa.w;
    }
#pragma unroll
    for (int p = 0; p < 2; ++p) {
      int c4 = c4b + 4 * p;
      float4 fb = *(const float4*)(B + (size_t)(bn + rowB) * 512 + k0 + c4 * 4);
      Bs[c4 * 4 + 0][rowB] = fb.x; Bs[c4 * 4 + 1][rowB] = fb.y;
      Bs[c4 * 4 + 2][rowB] = fb.z; Bs[c4 * 4 + 3][rowB] = fb.w;
    }
    __syncthreads();
#pragma unroll
    for (int kk = 0; kk < 32; ++kk) {
      float a[8], b[4];
      *(float4*)&a[0] = *(const float4*)&As[kk][ty * 8];
      *(float4*)&a[4] = *(const float4*)&As[kk][ty * 8 + 4];
      *(float4*)&b[0] = *(const float4*)&Bs[kk][tx * 4];
#pragma unroll
      for (int i = 0; i < 8; ++i)
#pragma unroll
        for (int j = 0; j < 4; ++j) acc[i][j] += a[i] * b[j];
    }
    __syncthreads();
  }

#pragma unroll
  for (int i = 0; i < 8; ++i) {
    size_t row = bm + ty * 8 + i;
    float4 r;
    r.x = acc[i][0]; r.y = acc[i][1]; r.z = acc[i][2]; r.w = acc[i][3];
    *(float4*)(C + row * (size_t)TQKV + bn + tx * 4) = r;
  }
}

// ---------------------------------------------------------------------------
// 2-way split fp32 -> (hi, lo*2^11).
// ---------------------------------------------------------------------------
__global__ __launch_bounds__(256) void split_f16_k(
    const float* __restrict__ s, _Float16* __restrict__ hi,
    _Float16* __restrict__ lo, int n4) {
  int i = blockIdx.x * 256 + threadIdx.x;
  if (i >= n4) return;
  float4 a = ((const float4*)s)[i];
  half4 h, l;
  float av[4] = {a.x, a.y, a.z, a.w};
#pragma unroll
  for (int j = 0; j < 4; ++j) {
    _Float16 hh = (_Float16)av[j];
    h[j] = hh;
    l[j] = (_Float16)((av[j] - (float)hh) * 2048.0f);
  }
  ((half4*)hi)[i] = h;
  ((half4*)lo)[i] = l;
}

// ---------------------------------------------------------------------------
// 2-term split-f16 NT GEMM via MFMA (proven). vGEMM and GEMM2.
// ---------------------------------------------------------------------------
__global__ __launch_bounds__(256) void gemm_split_nt(
    const _Float16* __restrict__ Ah, const _Float16* __restrict__ Al,
    const _Float16* __restrict__ Bh, const _Float16* __restrict__ Bl,
    const float* __restrict__ bias, float* __restrict__ C,
    int Ndim, int Kd) {
  constexpr int BM = 128, BN = 64, BK = 32;
  __shared__ _Float16 lds[(2 * BM + 2 * BN) * BK];  // 24 KB
  constexpr int AHo = 0;
  constexpr int ALo = BM * BK;
  constexpr int BHo = 2 * BM * BK;
  constexpr int BLo = 2 * BM * BK + BN * BK;

  const int tid = threadIdx.x;
  const int wave = tid >> 6, lane = tid & 63;
  const int lq = lane >> 4, lm = lane & 15;
  const int bm = blockIdx.y * BM, bn = blockIdx.x * BN;

  f32x4 acc[2][4] = {};
  f32x4 corr[2][4] = {};

  const int nsteps = Kd >> 5;
  for (int ks = 0; ks < nsteps; ++ks) {
    const int k0 = ks * BK;
    for (int idx = wave; idx < 24; idx += 4) {
      int t, j;
      if (idx < 8)       { t = 0; j = idx; }
      else if (idx < 16) { t = 1; j = idx - 8; }
      else if (idx < 20) { t = 2; j = idx - 16; }
      else               { t = 3; j = idx - 20; }
      const int row = j * 16 + (lane >> 2);
      const _Float16* g;
      _Float16* l;
      if (t == 0)      { g = Ah + (size_t)(bm + row) * Kd; l = lds + AHo + j * 16 * BK; }
      else if (t == 1) { g = Al + (size_t)(bm + row) * Kd; l = lds + ALo + j * 16 * BK; }
      else if (t == 2) { g = Bh + (size_t)(bn + row) * Kd; l = lds + BHo + j * 16 * BK; }
      else             { g = Bl + (size_t)(bn + row) * Kd; l = lds + BLo + j * 16 * BK; }
      g += k0 + (lane & 3) * 8;
      __builtin_amdgcn_global_load_lds(AS1(g), AS3(l), 16, 0, 0);
    }
    __syncthreads();

    half8 ahf[2], alf[2], bhf[4], blf[4];
    const int mwo = wave * 32;
#pragma unroll
    for (int fi = 0; fi < 2; ++fi) {
      ahf[fi] = *(const half8*)&lds[AHo + (mwo + fi * 16 + lm) * BK + lq * 8];
      alf[fi] = *(const half8*)&lds[ALo + (mwo + fi * 16 + lm) * BK + lq * 8];
    }
#pragma unroll
    for (int fj = 0; fj < 4; ++fj) {
      bhf[fj] = *(const half8*)&lds[BHo + (fj * 16 + lm) * BK + lq * 8];
      blf[fj] = *(const half8*)&lds[BLo + (fj * 16 + lm) * BK + lq * 8];
    }
#pragma unroll
    for (int fi = 0; fi < 2; ++fi)
#pragma unroll
      for (int fj = 0; fj < 4; ++fj) {
        acc[fi][fj] = __builtin_amdgcn_mfma_f32_16x16x32_f16(
            ahf[fi], bhf[fj], acc[fi][fj], 0, 0, 0);
        corr[fi][fj] = __builtin_amdgcn_mfma_f32_16x16x32_f16(
            ahf[fi], blf[fj], corr[fi][fj], 0, 0, 0);
        corr[fi][fj] = __builtin_amdgcn_mfma_f32_16x16x32_f16(
            alf[fi], bhf[fj], corr[fi][fj], 0, 0, 0);
      }
    __syncthreads();
  }

#pragma unroll
  for (int fi = 0; fi < 2; ++fi) {
    const int m0 = bm + wave * 32 + fi * 16 + lq * 4;
#pragma unroll
    for (int fj = 0; fj < 4; ++fj) {
      const int n = bn + fj * 16 + lm;
      const float bb = bias ? bias[n] : 0.f;
      f32x4 v = acc[fi][fj];
      f32x4 cv = corr[fi][fj];
#pragma unroll
      for (int r = 0; r < 4; ++r)
        C[(size_t)(m0 + r) * Ndim + n] = v[r] + cv[r] * (1.0f / 2048.0f) + bb;
    }
  }
}

// ---------------------------------------------------------------------------
// Pass 1 (FUSED LN), R22: 512 threads (16 waves/CU vs 8 — R21 coop profile
// showed the tail is latency-bound at VALUBusy 8%). Per-thread sums tile
// 4x4 -> 4x2 (e0 split); every output's n-ascending fp32 chain unchanged
// => BIT-IDENTICAL to the 256-thread version.
// ---------------------------------------------------------------------------
__global__ __launch_bounds__(512) void chunk_sums_ln(
    float* __restrict__ qkv, const float* __restrict__ lnk_w,
    const float* __restrict__ lnk_b, const float* __restrict__ lnv_w,
    const float* __restrict__ lnv_b, float* __restrict__ cbuf) {
  int blk = blockIdx.x;
  int c = blk % NCH;
  int bh = blk / NCH;
  int h = bh % Hh, b = bh / Hh;
  __shared__ float Ks[CH][68];
  __shared__ float Vs[CH][68];
  int tid = threadIdx.x;
  float* base = qkv + (size_t)(b * Nn + c * CH) * TQKV + h * Dd;
  for (int i = tid; i < CH * 16; i += 512) {
    int row = i >> 4, c4 = i & 15;
    *(float4*)&Ks[row][c4 * 4] =
        *(const float4*)(base + (size_t)row * TQKV + INNER + c4 * 4);
    *(float4*)&Vs[row][c4 * 4] =
        *(const float4*)(base + (size_t)row * TQKV + 2 * INNER + c4 * 4);
  }
  __syncthreads();

  if (tid < 128) {
    bool isv = tid >= 64;
    int row = tid & 63;
    float* R = isv ? &Vs[row][0] : &Ks[row][0];
    float s = 0.f, s2 = 0.f;
#pragma unroll
    for (int j = 0; j < 64; j += 4) {
      float4 v = *(const float4*)&R[j];
      s += v.x + v.y + v.z + v.w;
      s2 += v.x * v.x + v.y * v.y + v.z * v.z + v.w * v.w;
    }
    float mean = s * (1.f / 64.f);
    float var = s2 * (1.f / 64.f) - mean * mean;
    float inv = 1.0f / sqrtf(var + EPSF);
    const float* w = isv ? lnv_w : lnk_w;
    const float* bb = isv ? lnv_b : lnk_b;
#pragma unroll
    for (int j = 0; j < 64; ++j)
      R[j] = (R[j] - mean) * inv * w[h * Dd + j] + bb[h * Dd + j];
  }
  __syncthreads();

  for (int i = tid; i < CH * 16; i += 512) {
    int row = i >> 4, c4 = i & 15;
    *(float4*)(base + (size_t)row * TQKV + INNER + c4 * 4) =
        *(const float4*)&Ks[row][c4 * 4];
    *(float4*)(base + (size_t)row * TQKV + 2 * INNER + c4 * 4) =
        *(const float4*)&Vs[row][c4 * 4];
  }

  // sums: 512 threads, per-thread 4 (d) x 2 (e)
  int d0 = (tid >> 5) * 4;        // 0..60
  int e0 = (tid & 31) * 2;        // 0..62
  float acc[4][2] = {};
  float kc[4] = {0.f, 0.f, 0.f, 0.f};
  for (int n = 0; n < CH; ++n) {
    float4 kv = *(const float4*)&Ks[n][d0];
    float2 vv = *(const float2*)&Vs[n][e0];
    float ka[4] = {kv.x, kv.y, kv.z, kv.w};
    float va[2] = {vv.x, vv.y};
#pragma unroll
    for (int i = 0; i < 4; ++i)
#pragma unroll
      for (int j = 0; j < 2; ++j) acc[i][j] += ka[i] * va[j];
    if (e0 == 0) {
#pragma unroll
      for (int i = 0; i < 4; ++i) kc[i] += ka[i];
    }
  }
  float* out = cbuf + (size_t)blk * CSZ;
#pragma unroll
  for (int i = 0; i < 4; ++i) {
    float2 r;
    r.x = acc[i][0]; r.y = acc[i][1];
    *(float2*)(out + (size_t)(d0 + i) * Dd + e0) = r;
  }
  if (e0 == 0) {
#pragma unroll
    for (int i = 0; i < 4; ++i) out[Dd * Dd + d0 + i] = kc[i];
  }
}

// ---------------------------------------------------------------------------
// Pass 2: exclusive prefix over chunks, parallel over columns. (unchanged)
// ---------------------------------------------------------------------------
__global__ __launch_bounds__(256) void chunk_prefix(float* __restrict__ cbuf) {
  int bh = blockIdx.y;
  int i = blockIdx.x * 256 + threadIdx.x;
  if (i >= CSZ) return;
  float* p = cbuf + (size_t)bh * NCH * CSZ + i;
  float carry = 0.f;
  for (int c = 0; c < NCH; ++c) {
    float t = p[(size_t)c * CSZ];
    p[(size_t)c * CSZ] = carry;
    carry += t;
  }
}

// ---------------------------------------------------------------------------
// Pass 3, R22: 512 threads (16 waves/CU). Per-thread tiles 4x4 -> 2x4
// (rows n = ty*2+i, ty 0..31). All FMA chains (kk/d/m ascending) and rs/
// denom structure unchanged => BIT-IDENTICAL outputs.
// ---------------------------------------------------------------------------
__global__ __launch_bounds__(512) void chunk_attn(
    const float* __restrict__ qkv, const float* __restrict__ cbuf,
    _Float16* __restrict__ atth, _Float16* __restrict__ attl) {
  int blk = blockIdx.x;
  int c = blk % NCH;
  int bh = blk / NCH;
  int h = bh % Hh, b = bh / Hh;
  __shared__ float Qs[64][68];   // [d][n]
  __shared__ float Ks[64][68];   // [d][m]; later reused as Ps[m][n]
  __shared__ float Vs[64][68];   // [m][e]
  __shared__ float Ss[64][68];   // [d][e]
  __shared__ float kcs[64];
  __shared__ float rs[64][17];
  __shared__ float denomS[64];
  float (*Ps)[68] = Ks;          // overlay

  int tid = threadIdx.x;
  int tx = tid & 15, ty = tid >> 4;   // ty 0..31
  const float* base = qkv + (size_t)(b * Nn + c * CH) * TQKV + h * Dd;
  for (int i = tid; i < CH * 16; i += 512) {
    int row = i >> 4, c4 = i & 15;
    float4 fq = *(const float4*)(base + (size_t)row * TQKV + c4 * 4);
    Qs[c4 * 4 + 0][row] = fq.x; Qs[c4 * 4 + 1][row] = fq.y;
    Qs[c4 * 4 + 2][row] = fq.z; Qs[c4 * 4 + 3][row] = fq.w;
    float4 fk = *(const float4*)(base + (size_t)row * TQKV + INNER + c4 * 4);
    Ks[c4 * 4 + 0][row] = fk.x; Ks[c4 * 4 + 1][row] = fk.y;
    Ks[c4 * 4 + 2][row] = fk.z; Ks[c4 * 4 + 3][row] = fk.w;
    float4 fv = *(const float4*)(base + (size_t)row * TQKV + 2 * INNER + c4 * 4);
    *(float4*)&Vs[row][c4 * 4] = fv;
  }
  const float* sp = cbuf + (size_t)blk * CSZ;
  for (int i = tid; i < 1024; i += 512) {
    int row = i >> 4;
    *(float4*)&Ss[row][(i & 15) * 4] = *(const float4*)(sp + (size_t)i * 4);
  }
  if (tid < 16) {
    float4 f = *(const float4*)(sp + Dd * Dd + tid * 4);
    kcs[tid * 4 + 0] = f.x; kcs[tid * 4 + 1] = f.y;
    kcs[tid * 4 + 2] = f.z; kcs[tid * 4 + 3] = f.w;
  }
  __syncthreads();

  // P = Q K^T into registers (rows n = ty*2 + i)
  float accP[2][4] = {};
  for (int kk = 0; kk < 64; ++kk) {
    float2 qa = *(const float2*)&Qs[kk][ty * 2];
    float4 kb = *(const float4*)&Ks[kk][tx * 4];
    float qv[2] = {qa.x, qa.y};
    float kv[4] = {kb.x, kb.y, kb.z, kb.w};
#pragma unroll
    for (int i = 0; i < 2; ++i)
#pragma unroll
      for (int j = 0; j < 4; ++j) accP[i][j] += qv[i] * kv[j];
  }
  __syncthreads();  // Ks reads done before Ps overlay is written

#pragma unroll
  for (int i = 0; i < 2; ++i) {
    int n = ty * 2 + i;
    float rsum = 0.f;
#pragma unroll
    for (int j = 0; j < 4; ++j) {
      int m = tx * 4 + j;
      float p = (m <= n) ? accP[i][j] : 0.f;
      Ps[m][n] = p;
      rsum += p;
    }
    rs[n][tx] = rsum;
  }
  __syncthreads();

  // O = Q * S_prefix; denom
  float accO[2][4] = {};
  for (int d = 0; d < 64; ++d) {
    float2 qa = *(const float2*)&Qs[d][ty * 2];
    float4 sb = *(const float4*)&Ss[d][tx * 4];
    float qv[2] = {qa.x, qa.y};
    float sv[4] = {sb.x, sb.y, sb.z, sb.w};
#pragma unroll
    for (int i = 0; i < 2; ++i)
#pragma unroll
      for (int j = 0; j < 4; ++j) accO[i][j] += qv[i] * sv[j];
  }
  if (tid < 64) {
    int n = tid;
    float qkc = 0.f, qs = 0.f;
    for (int d = 0; d < 64; ++d) {
      float q = Qs[d][n];
      qkc += q * kcs[d];
      qs += q;
    }
    float rsum = 0.f;
#pragma unroll
    for (int t2 = 0; t2 < 16; ++t2) rsum += rs[n][t2];
    denomS[n] = qkc + rsum + EPSF * qs;
  }
  __syncthreads();

  // O += P_masked * V
  for (int m = 0; m < 64; ++m) {
    float2 pa = *(const float2*)&Ps[m][ty * 2];
    float4 vb = *(const float4*)&Vs[m][tx * 4];
    float pv[2] = {pa.x, pa.y};
    float vv[4] = {vb.x, vb.y, vb.z, vb.w};
#pragma unroll
    for (int i = 0; i < 2; ++i)
#pragma unroll
      for (int j = 0; j < 4; ++j) accO[i][j] += pv[i] * vv[j];
  }

  size_t obase = (size_t)(b * Nn + c * CH) * INNER + h * Dd;
#pragma unroll
  for (int i = 0; i < 2; ++i) {
    int n = ty * 2 + i;
    float dinv = 1.0f / denomS[n];
    float scale = dinv * (1.0f / (float)Nn);
    half4 hv, lv;
#pragma unroll
    for (int j = 0; j < 4; ++j) {
      float o = accO[i][j] * scale;
      _Float16 hh = (_Float16)o;
      hv[j] = hh;
      lv[j] = (_Float16)((o - (float)hh) * 2048.0f);
    }
    *(half4*)(atth + obase + (size_t)n * INNER + tx * 4) = hv;
    *(half4*)(attl + obase + (size_t)n * INNER + tx * 4) = lv;
  }
}

// ---------------------------------------------------------------------------
extern "C" void kernel_launch(void* const* d_in, const int* in_sizes, int n_in,
                              void* d_out, int out_size, void* d_ws,
                              size_t ws_size, hipStream_t stream) {
  const float* x     = (const float*)d_in[0];
  const float* w_qkv = (const float*)d_in[1];
  const float* lnk_w = (const float*)d_in[2];
  const float* lnk_b = (const float*)d_in[3];
  const float* lnv_w = (const float*)d_in[4];
  const float* lnv_b = (const float*)d_in[5];
  const float* w_out = (const float*)d_in[6];
  const float* b_out = (const float*)d_in[7];
  float* out = (float*)d_out;

  // Workspace layout (~52.56 MB, the exact R0-proven layout):
  float* qkv  = (float*)d_ws;                      // 4096*1536 fp32
  float* cbuf = qkv + (size_t)Mm * TQKV;           // 512*4160 fp32
  _Float16* atth = (_Float16*)(cbuf + (size_t)Bb * Hh * NCH * CSZ);
  _Float16* attl = atth + (size_t)Mm * INNER;
  _Float16* woh  = attl + (size_t)Mm * INNER;
  _Float16* wol  = woh + (size_t)INNER * 512;
  _Float16* xh   = wol + (size_t)INNER * 512;      // x split 4096x512
  _Float16* xl   = xh + (size_t)Mm * 512;
  _Float16* wvh  = xl + (size_t)Mm * 512;          // w_qkv v-rows split 512x512
  _Float16* wvl  = wvh + (size_t)INNER * 512;

  // 1a. Split x and the v-rows of w_qkv (rows 1024..1535)
  split_f16_k<<<2048, 256, 0, stream>>>(x, xh, xl, Mm * 512 / 4);
  split_f16_k<<<256, 256, 0, stream>>>(
      w_qkv + (size_t)1024 * 512, wvh, wvl, INNER * 512 / 4);

  // 1b. GEMM1-qk (fp32 VALU, N=1024): R0-exact (71.9 us proven)
  gemm1_f32<<<dim3(1024 / 64, Mm / 128), 256, 0, stream>>>(x, w_qkv, qkv);

  // 1c. GEMM1-v (2-term split MFMA, N=512): writes qkv cols 1024..1535
  gemm_split_nt<<<dim3(512 / 64, Mm / 128), 256, 0, stream>>>(
      xh, xl, wvh, wvl, nullptr, qkv + 1024, TQKV, 512);

  // 2. Fused LN(k,v) + per-chunk K^T V + colsum(K) — 512 threads
  chunk_sums_ln<<<Bb * Hh * NCH, 512, 0, stream>>>(
      qkv, lnk_w, lnk_b, lnv_w, lnv_b, cbuf);

  // 3. Exclusive prefix over chunks (parallel over columns)
  chunk_prefix<<<dim3((CSZ + 255) / 256, Bb * Hh), 256, 0, stream>>>(cbuf);

  // 4. Split w_out for GEMM2
  split_f16_k<<<256, 256, 0, stream>>>(w_out, woh, wol, INNER * 512 / 4);

  // 5. Per-chunk attention -> attn split f16 — 512 threads
  chunk_attn<<<Bb * Hh * NCH, 512, 0, stream>>>(qkv, cbuf, atth, attl);

  // 6. Output GEMM: out = attn * w_out^T + b_out (2-term split MFMA)
  gemm_split_nt<<<dim3(INNER / 64, Mm / 128), 256, 0, stream>>>(
      atth, attl, woh, wol, b_out, out, INNER, 512);
}

// Round 14
// 232.737 us; speedup vs baseline: 1.7590x; 1.7590x over previous
//
#include <hip/hip_runtime.h>

// Problem constants
constexpr int Bb   = 2;
constexpr int Nn   = 2048;
constexpr int Hh   = 8;
constexpr int Dd   = 64;
constexpr int Mm   = Bb * Nn;      // 4096 rows
constexpr int TQKV = 1536;         // 3 * H * D
constexpr int INNER = Hh * Dd;     // 512
constexpr int CH   = 64;           // chunk length
constexpr int NCH  = Nn / CH;      // 32 chunks per (b,h)
constexpr int CSZ  = Dd * Dd + Dd; // 4160 floats per chunk record (S + kc)
constexpr float EPSF = 1e-7f;

typedef _Float16 half8 __attribute__((ext_vector_type(8)));
typedef _Float16 half4 __attribute__((ext_vector_type(4)));
typedef float f32x4 __attribute__((ext_vector_type(4)));

#define AS1(p) ((const __attribute__((address_space(1))) unsigned int*)(p))
#define AS3(p) ((__attribute__((address_space(3))) unsigned int*)(p))

// ---------------------------------------------------------------------------
// GEMM1-qk (fp32 VALU): R0-EXACT (71.9 us proven floor; R15-R18 all failed
// to beat it). q,k MUST stay fp32-VALU (R11-R14: MFMA split fails at absmax
// 1.0-1.375 via denominator amplification).
// R23: tail reverted to 256-thread proven kernels — R22's 512-thread attn
// spilled accumulators to scratch (FETCH 267MB/WRITE 352MB per dispatch,
// ~2KB/thread loop-resident spill traffic => HBM-bound 193us). The attn
// kernel needs ~112-128 VGPR/thread; >8 waves/CU is structurally
// unreachable without spill. Wave-count lever on the tail: DEAD.
// ---------------------------------------------------------------------------
__global__ __launch_bounds__(256) void gemm1_f32(
    const float* __restrict__ A, const float* __restrict__ B,
    float* __restrict__ C) {
  __shared__ float As[32][132];  // [k][m]
  __shared__ float Bs[32][68];   // [k][n]
  const int tid = threadIdx.x;
  const int tx = tid & 15, ty = tid >> 4;
  const int bm = blockIdx.y * 128, bn = blockIdx.x * 64;
  const int rowA = tid & 127, c4a = tid >> 7;  // 0..1
  const int rowB = tid & 63,  c4b = tid >> 6;  // 0..3

  float acc[8][4] = {};

  for (int k0 = 0; k0 < 512; k0 += 32) {
#pragma unroll
    for (int p = 0; p < 4; ++p) {
      int c4 = c4a + 2 * p;
      float4 fa = *(const float4*)(A + (size_t)(bm + rowA) * 512 + k0 + c4 * 4);
      As[c4 * 4 + 0][rowA] = fa.x; As[c4 * 4 + 1][rowA] = fa.y;
      As[c4 * 4 + 2][rowA] = fa.z; As[c4 * 4 + 3][rowA] = fa.w;
    }
#pragma unroll
    for (int p = 0; p < 2; ++p) {
      int c4 = c4b + 4 * p;
      float4 fb = *(const float4*)(B + (size_t)(bn + rowB) * 512 + k0 + c4 * 4);
      Bs[c4 * 4 + 0][rowB] = fb.x; Bs[c4 * 4 + 1][rowB] = fb.y;
      Bs[c4 * 4 + 2][rowB] = fb.z; Bs[c4 * 4 + 3][rowB] = fb.w;
    }
    __syncthreads();
#pragma unroll
    for (int kk = 0; kk < 32; ++kk) {
      float a[8], b[4];
      *(float4*)&a[0] = *(const float4*)&As[kk][ty * 8];
      *(float4*)&a[4] = *(const float4*)&As[kk][ty * 8 + 4];
      *(float4*)&b[0] = *(const float4*)&Bs[kk][tx * 4];
#pragma unroll
      for (int i = 0; i < 8; ++i)
#pragma unroll
        for (int j = 0; j < 4; ++j) acc[i][j] += a[i] * b[j];
    }
    __syncthreads();
  }

#pragma unroll
  for (int i = 0; i < 8; ++i) {
    size_t row = bm + ty * 8 + i;
    float4 r;
    r.x = acc[i][0]; r.y = acc[i][1]; r.z = acc[i][2]; r.w = acc[i][3];
    *(float4*)(C + row * (size_t)TQKV + bn + tx * 4) = r;
  }
}

// ---------------------------------------------------------------------------
// R23: ONE split dispatch for x, w_qkv v-rows, and w_out (was 3 dispatches;
// also removes the w_out split from between prefix and attn in the tail).
// Per-element expression identical to the proven split_f16_k => bit-identical.
// Block ranges: [0,2048) x ; [2048,2304) wv ; [2304,2560) w_out.
// ---------------------------------------------------------------------------
__global__ __launch_bounds__(256) void split_all(
    const float* __restrict__ x, const float* __restrict__ wv,
    const float* __restrict__ wout,
    _Float16* __restrict__ xh, _Float16* __restrict__ xl,
    _Float16* __restrict__ wvh, _Float16* __restrict__ wvl,
    _Float16* __restrict__ woh, _Float16* __restrict__ wol) {
  const int blk = blockIdx.x;
  const float* s;
  _Float16 *hi, *lo;
  int i;
  if (blk < 2048) {
    s = x; hi = xh; lo = xl; i = blk * 256 + threadIdx.x;
  } else if (blk < 2304) {
    s = wv; hi = wvh; lo = wvl; i = (blk - 2048) * 256 + threadIdx.x;
  } else {
    s = wout; hi = woh; lo = wol; i = (blk - 2304) * 256 + threadIdx.x;
  }
  float4 a = ((const float4*)s)[i];
  half4 h, l;
  float av[4] = {a.x, a.y, a.z, a.w};
#pragma unroll
  for (int j = 0; j < 4; ++j) {
    _Float16 hh = (_Float16)av[j];
    h[j] = hh;
    l[j] = (_Float16)((av[j] - (float)hh) * 2048.0f);
  }
  ((half4*)hi)[i] = h;
  ((half4*)lo)[i] = l;
}

// ---------------------------------------------------------------------------
// 2-term split-f16 NT GEMM via MFMA (proven). vGEMM and GEMM2.
// ---------------------------------------------------------------------------
__global__ __launch_bounds__(256) void gemm_split_nt(
    const _Float16* __restrict__ Ah, const _Float16* __restrict__ Al,
    const _Float16* __restrict__ Bh, const _Float16* __restrict__ Bl,
    const float* __restrict__ bias, float* __restrict__ C,
    int Ndim, int Kd) {
  constexpr int BM = 128, BN = 64, BK = 32;
  __shared__ _Float16 lds[(2 * BM + 2 * BN) * BK];  // 24 KB
  constexpr int AHo = 0;
  constexpr int ALo = BM * BK;
  constexpr int BHo = 2 * BM * BK;
  constexpr int BLo = 2 * BM * BK + BN * BK;

  const int tid = threadIdx.x;
  const int wave = tid >> 6, lane = tid & 63;
  const int lq = lane >> 4, lm = lane & 15;
  const int bm = blockIdx.y * BM, bn = blockIdx.x * BN;

  f32x4 acc[2][4] = {};
  f32x4 corr[2][4] = {};

  const int nsteps = Kd >> 5;
  for (int ks = 0; ks < nsteps; ++ks) {
    const int k0 = ks * BK;
    for (int idx = wave; idx < 24; idx += 4) {
      int t, j;
      if (idx < 8)       { t = 0; j = idx; }
      else if (idx < 16) { t = 1; j = idx - 8; }
      else if (idx < 20) { t = 2; j = idx - 16; }
      else               { t = 3; j = idx - 20; }
      const int row = j * 16 + (lane >> 2);
      const _Float16* g;
      _Float16* l;
      if (t == 0)      { g = Ah + (size_t)(bm + row) * Kd; l = lds + AHo + j * 16 * BK; }
      else if (t == 1) { g = Al + (size_t)(bm + row) * Kd; l = lds + ALo + j * 16 * BK; }
      else if (t == 2) { g = Bh + (size_t)(bn + row) * Kd; l = lds + BHo + j * 16 * BK; }
      else             { g = Bl + (size_t)(bn + row) * Kd; l = lds + BLo + j * 16 * BK; }
      g += k0 + (lane & 3) * 8;
      __builtin_amdgcn_global_load_lds(AS1(g), AS3(l), 16, 0, 0);
    }
    __syncthreads();

    half8 ahf[2], alf[2], bhf[4], blf[4];
    const int mwo = wave * 32;
#pragma unroll
    for (int fi = 0; fi < 2; ++fi) {
      ahf[fi] = *(const half8*)&lds[AHo + (mwo + fi * 16 + lm) * BK + lq * 8];
      alf[fi] = *(const half8*)&lds[ALo + (mwo + fi * 16 + lm) * BK + lq * 8];
    }
#pragma unroll
    for (int fj = 0; fj < 4; ++fj) {
      bhf[fj] = *(const half8*)&lds[BHo + (fj * 16 + lm) * BK + lq * 8];
      blf[fj] = *(const half8*)&lds[BLo + (fj * 16 + lm) * BK + lq * 8];
    }
#pragma unroll
    for (int fi = 0; fi < 2; ++fi)
#pragma unroll
      for (int fj = 0; fj < 4; ++fj) {
        acc[fi][fj] = __builtin_amdgcn_mfma_f32_16x16x32_f16(
            ahf[fi], bhf[fj], acc[fi][fj], 0, 0, 0);
        corr[fi][fj] = __builtin_amdgcn_mfma_f32_16x16x32_f16(
            ahf[fi], blf[fj], corr[fi][fj], 0, 0, 0);
        corr[fi][fj] = __builtin_amdgcn_mfma_f32_16x16x32_f16(
            alf[fi], bhf[fj], corr[fi][fj], 0, 0, 0);
      }
    __syncthreads();
  }

#pragma unroll
  for (int fi = 0; fi < 2; ++fi) {
    const int m0 = bm + wave * 32 + fi * 16 + lq * 4;
#pragma unroll
    for (int fj = 0; fj < 4; ++fj) {
      const int n = bn + fj * 16 + lm;
      const float bb = bias ? bias[n] : 0.f;
      f32x4 v = acc[fi][fj];
      f32x4 cv = corr[fi][fj];
#pragma unroll
      for (int r = 0; r < 4; ++r)
        C[(size_t)(m0 + r) * Ndim + n] = v[r] + cv[r] * (1.0f / 2048.0f) + bb;
    }
  }
}

// ---------------------------------------------------------------------------
// Pass 1 (FUSED LN): LN(k,v) in LDS + writeback + S_c = K^T V + colsum(K).
// 256-thread proven version (R0-exact).
// ---------------------------------------------------------------------------
__global__ __launch_bounds__(256) void chunk_sums_ln(
    float* __restrict__ qkv, const float* __restrict__ lnk_w,
    const float* __restrict__ lnk_b, const float* __restrict__ lnv_w,
    const float* __restrict__ lnv_b, float* __restrict__ cbuf) {
  int blk = blockIdx.x;
  int c = blk % NCH;
  int bh = blk / NCH;
  int h = bh % Hh, b = bh / Hh;
  __shared__ float Ks[CH][68];
  __shared__ float Vs[CH][68];
  int tid = threadIdx.x;
  float* base = qkv + (size_t)(b * Nn + c * CH) * TQKV + h * Dd;
  for (int i = tid; i < CH * 16; i += 256) {
    int row = i >> 4, c4 = i & 15;
    *(float4*)&Ks[row][c4 * 4] =
        *(const float4*)(base + (size_t)row * TQKV + INNER + c4 * 4);
    *(float4*)&Vs[row][c4 * 4] =
        *(const float4*)(base + (size_t)row * TQKV + 2 * INNER + c4 * 4);
  }
  __syncthreads();

  if (tid < 128) {
    bool isv = tid >= 64;
    int row = tid & 63;
    float* R = isv ? &Vs[row][0] : &Ks[row][0];
    float s = 0.f, s2 = 0.f;
#pragma unroll
    for (int j = 0; j < 64; j += 4) {
      float4 v = *(const float4*)&R[j];
      s += v.x + v.y + v.z + v.w;
      s2 += v.x * v.x + v.y * v.y + v.z * v.z + v.w * v.w;
    }
    float mean = s * (1.f / 64.f);
    float var = s2 * (1.f / 64.f) - mean * mean;
    float inv = 1.0f / sqrtf(var + EPSF);
    const float* w = isv ? lnv_w : lnk_w;
    const float* bb = isv ? lnv_b : lnk_b;
#pragma unroll
    for (int j = 0; j < 64; ++j)
      R[j] = (R[j] - mean) * inv * w[h * Dd + j] + bb[h * Dd + j];
  }
  __syncthreads();

  for (int i = tid; i < CH * 16; i += 256) {
    int row = i >> 4, c4 = i & 15;
    *(float4*)(base + (size_t)row * TQKV + INNER + c4 * 4) =
        *(const float4*)&Ks[row][c4 * 4];
    *(float4*)(base + (size_t)row * TQKV + 2 * INNER + c4 * 4) =
        *(const float4*)&Vs[row][c4 * 4];
  }

  int d0 = (tid >> 4) * 4, e0 = (tid & 15) * 4;
  float acc[4][4] = {};
  float kc[4] = {0.f, 0.f, 0.f, 0.f};
  for (int n = 0; n < CH; ++n) {
    float4 kv = *(const float4*)&Ks[n][d0];
    float4 vv = *(const float4*)&Vs[n][e0];
    float ka[4] = {kv.x, kv.y, kv.z, kv.w};
    float va[4] = {vv.x, vv.y, vv.z, vv.w};
#pragma unroll
    for (int i = 0; i < 4; ++i)
#pragma unroll
      for (int j = 0; j < 4; ++j) acc[i][j] += ka[i] * va[j];
    if (e0 == 0) {
#pragma unroll
      for (int i = 0; i < 4; ++i) kc[i] += ka[i];
    }
  }
  float* out = cbuf + (size_t)blk * CSZ;
#pragma unroll
  for (int i = 0; i < 4; ++i) {
    float4 r;
    r.x = acc[i][0]; r.y = acc[i][1]; r.z = acc[i][2]; r.w = acc[i][3];
    *(float4*)(out + (size_t)(d0 + i) * Dd + e0) = r;
  }
  if (e0 == 0) {
#pragma unroll
    for (int i = 0; i < 4; ++i) out[Dd * Dd + d0 + i] = kc[i];
  }
}

// ---------------------------------------------------------------------------
// Pass 2: exclusive prefix over chunks, parallel over columns.
// ---------------------------------------------------------------------------
__global__ __launch_bounds__(256) void chunk_prefix(float* __restrict__ cbuf) {
  int bh = blockIdx.y;
  int i = blockIdx.x * 256 + threadIdx.x;
  if (i >= CSZ) return;
  float* p = cbuf + (size_t)bh * NCH * CSZ + i;
  float carry = 0.f;
  for (int c = 0; c < NCH; ++c) {
    float t = p[(size_t)c * CSZ];
    p[(size_t)c * CSZ] = carry;
    carry += t;
  }
}

// ---------------------------------------------------------------------------
// Pass 3: per chunk attention; writes attn split to f16 hi/lo for GEMM2.
// 256-thread proven version (R0-exact). Ps overlays Ks (74.5 KB LDS).
// ---------------------------------------------------------------------------
__global__ __launch_bounds__(256) void chunk_attn(
    const float* __restrict__ qkv, const float* __restrict__ cbuf,
    _Float16* __restrict__ atth, _Float16* __restrict__ attl) {
  int blk = blockIdx.x;
  int c = blk % NCH;
  int bh = blk / NCH;
  int h = bh % Hh, b = bh / Hh;
  __shared__ float Qs[64][68];   // [d][n]
  __shared__ float Ks[64][68];   // [d][m]; later reused as Ps[m][n]
  __shared__ float Vs[64][68];   // [m][e]
  __shared__ float Ss[64][68];   // [d][e]
  __shared__ float kcs[64];
  __shared__ float rs[64][17];
  __shared__ float denomS[64];
  float (*Ps)[68] = Ks;          // overlay

  int tid = threadIdx.x;
  int tx = tid & 15, ty = tid >> 4;
  const float* base = qkv + (size_t)(b * Nn + c * CH) * TQKV + h * Dd;
  for (int i = tid; i < CH * 16; i += 256) {
    int row = i >> 4, c4 = i & 15;
    float4 fq = *(const float4*)(base + (size_t)row * TQKV + c4 * 4);
    Qs[c4 * 4 + 0][row] = fq.x; Qs[c4 * 4 + 1][row] = fq.y;
    Qs[c4 * 4 + 2][row] = fq.z; Qs[c4 * 4 + 3][row] = fq.w;
    float4 fk = *(const float4*)(base + (size_t)row * TQKV + INNER + c4 * 4);
    Ks[c4 * 4 + 0][row] = fk.x; Ks[c4 * 4 + 1][row] = fk.y;
    Ks[c4 * 4 + 2][row] = fk.z; Ks[c4 * 4 + 3][row] = fk.w;
    float4 fv = *(const float4*)(base + (size_t)row * TQKV + 2 * INNER + c4 * 4);
    *(float4*)&Vs[row][c4 * 4] = fv;
  }
  const float* sp = cbuf + (size_t)blk * CSZ;
  for (int i = tid; i < 1024; i += 256) {
    int row = i >> 4;
    *(float4*)&Ss[row][(i & 15) * 4] = *(const float4*)(sp + (size_t)i * 4);
  }
  if (tid < 16) {
    float4 f = *(const float4*)(sp + Dd * Dd + tid * 4);
    kcs[tid * 4 + 0] = f.x; kcs[tid * 4 + 1] = f.y;
    kcs[tid * 4 + 2] = f.z; kcs[tid * 4 + 3] = f.w;
  }
  __syncthreads();

  // P = Q K^T into registers
  float accP[4][4] = {};
  for (int kk = 0; kk < 64; ++kk) {
    float4 qa = *(const float4*)&Qs[kk][ty * 4];
    float4 kb = *(const float4*)&Ks[kk][tx * 4];
    float qv[4] = {qa.x, qa.y, qa.z, qa.w};
    float kv[4] = {kb.x, kb.y, kb.z, kb.w};
#pragma unroll
    for (int i = 0; i < 4; ++i)
#pragma unroll
      for (int j = 0; j < 4; ++j) accP[i][j] += qv[i] * kv[j];
  }
  __syncthreads();  // Ks reads done before Ps overlay is written

#pragma unroll
  for (int i = 0; i < 4; ++i) {
    int n = ty * 4 + i;
    float rsum = 0.f;
#pragma unroll
    for (int j = 0; j < 4; ++j) {
      int m = tx * 4 + j;
      float p = (m <= n) ? accP[i][j] : 0.f;
      Ps[m][n] = p;
      rsum += p;
    }
    rs[n][tx] = rsum;
  }
  __syncthreads();

  // O = Q * S_prefix; denom
  float accO[4][4] = {};
  for (int d = 0; d < 64; ++d) {
    float4 qa = *(const float4*)&Qs[d][ty * 4];
    float4 sb = *(const float4*)&Ss[d][tx * 4];
    float qv[4] = {qa.x, qa.y, qa.z, qa.w};
    float sv[4] = {sb.x, sb.y, sb.z, sb.w};
#pragma unroll
    for (int i = 0; i < 4; ++i)
#pragma unroll
      for (int j = 0; j < 4; ++j) accO[i][j] += qv[i] * sv[j];
  }
  if (tid < 64) {
    int n = tid;
    float qkc = 0.f, qs = 0.f;
    for (int d = 0; d < 64; ++d) {
      float q = Qs[d][n];
      qkc += q * kcs[d];
      qs += q;
    }
    float rsum = 0.f;
#pragma unroll
    for (int t2 = 0; t2 < 16; ++t2) rsum += rs[n][t2];
    denomS[n] = qkc + rsum + EPSF * qs;
  }
  __syncthreads();

  // O += P_masked * V
  for (int m = 0; m < 64; ++m) {
    float4 pa = *(const float4*)&Ps[m][ty * 4];
    float4 vb = *(const float4*)&Vs[m][tx * 4];
    float pv[4] = {pa.x, pa.y, pa.z, pa.w};
    float vv[4] = {vb.x, vb.y, vb.z, vb.w};
#pragma unroll
    for (int i = 0; i < 4; ++i)
#pragma unroll
      for (int j = 0; j < 4; ++j) accO[i][j] += pv[i] * vv[j];
  }

  size_t obase = (size_t)(b * Nn + c * CH) * INNER + h * Dd;
#pragma unroll
  for (int i = 0; i < 4; ++i) {
    int n = ty * 4 + i;
    float dinv = 1.0f / denomS[n];
    float scale = dinv * (1.0f / (float)Nn);
    half4 hv, lv;
#pragma unroll
    for (int j = 0; j < 4; ++j) {
      float o = accO[i][j] * scale;
      _Float16 hh = (_Float16)o;
      hv[j] = hh;
      lv[j] = (_Float16)((o - (float)hh) * 2048.0f);
    }
    *(half4*)(atth + obase + (size_t)n * INNER + tx * 4) = hv;
    *(half4*)(attl + obase + (size_t)n * INNER + tx * 4) = lv;
  }
}

// ---------------------------------------------------------------------------
extern "C" void kernel_launch(void* const* d_in, const int* in_sizes, int n_in,
                              void* d_out, int out_size, void* d_ws,
                              size_t ws_size, hipStream_t stream) {
  const float* x     = (const float*)d_in[0];
  const float* w_qkv = (const float*)d_in[1];
  const float* lnk_w = (const float*)d_in[2];
  const float* lnk_b = (const float*)d_in[3];
  const float* lnv_w = (const float*)d_in[4];
  const float* lnv_b = (const float*)d_in[5];
  const float* w_out = (const float*)d_in[6];
  const float* b_out = (const float*)d_in[7];
  float* out = (float*)d_out;

  // Workspace layout (~52.56 MB, the exact R0-proven layout):
  float* qkv  = (float*)d_ws;                      // 4096*1536 fp32
  float* cbuf = qkv + (size_t)Mm * TQKV;           // 512*4160 fp32
  _Float16* atth = (_Float16*)(cbuf + (size_t)Bb * Hh * NCH * CSZ);
  _Float16* attl = atth + (size_t)Mm * INNER;
  _Float16* woh  = attl + (size_t)Mm * INNER;
  _Float16* wol  = woh + (size_t)INNER * 512;
  _Float16* xh   = wol + (size_t)INNER * 512;      // x split 4096x512
  _Float16* xl   = xh + (size_t)Mm * 512;
  _Float16* wvh  = xl + (size_t)Mm * 512;          // w_qkv v-rows split 512x512
  _Float16* wvl  = wvh + (size_t)INNER * 512;

  // 1a. ONE split dispatch: x + w_qkv v-rows + w_out (was 3 dispatches)
  split_all<<<2560, 256, 0, stream>>>(
      x, w_qkv + (size_t)1024 * 512, w_out,
      xh, xl, wvh, wvl, woh, wol);

  // 1b. GEMM1-qk (fp32 VALU, N=1024): R0-exact (71.9 us proven)
  gemm1_f32<<<dim3(1024 / 64, Mm / 128), 256, 0, stream>>>(x, w_qkv, qkv);

  // 1c. GEMM1-v (2-term split MFMA, N=512): writes qkv cols 1024..1535
  gemm_split_nt<<<dim3(512 / 64, Mm / 128), 256, 0, stream>>>(
      xh, xl, wvh, wvl, nullptr, qkv + 1024, TQKV, 512);

  // 2. Fused LN(k,v) + per-chunk K^T V + colsum(K)
  chunk_sums_ln<<<Bb * Hh * NCH, 256, 0, stream>>>(
      qkv, lnk_w, lnk_b, lnv_w, lnv_b, cbuf);

  // 3. Exclusive prefix over chunks (parallel over columns)
  chunk_prefix<<<dim3((CSZ + 255) / 256, Bb * Hh), 256, 0, stream>>>(cbuf);

  // 4. Per-chunk attention -> attn split f16
  chunk_attn<<<Bb * Hh * NCH, 256, 0, stream>>>(qkv, cbuf, atth, attl);

  // 5. Output GEMM: out = attn * w_out^T + b_out (2-term split MFMA)
  gemm_split_nt<<<dim3(INNER / 64, Mm / 128), 256, 0, stream>>>(
      atth, attl, woh, wol, b_out, out, INNER, 512);
}

// Round 15
// 232.642 us; speedup vs baseline: 1.7597x; 1.0004x over previous
//
#include <hip/hip_runtime.h>

// Problem constants
constexpr int Bb   = 2;
constexpr int Nn   = 2048;
constexpr int Hh   = 8;
constexpr int Dd   = 64;
constexpr int Mm   = Bb * Nn;      // 4096 rows
constexpr int TQKV = 1536;         // 3 * H * D
constexpr int INNER = Hh * Dd;     // 512
constexpr int CH   = 64;           // chunk length
constexpr int NCH  = Nn / CH;      // 32 chunks per (b,h)
constexpr int CSZ  = Dd * Dd + Dd; // 4160 floats per chunk record (S + kc)
constexpr float EPSF = 1e-7f;

typedef _Float16 half8 __attribute__((ext_vector_type(8)));
typedef _Float16 half4 __attribute__((ext_vector_type(4)));
typedef float f32x4 __attribute__((ext_vector_type(4)));

#define AS1(p) ((const __attribute__((address_space(1))) unsigned int*)(p))
#define AS3(p) ((__attribute__((address_space(3))) unsigned int*)(p))

// ---------------------------------------------------------------------------
// GEMM1-qk (fp32 VALU): R0-EXACT (~70 us proven floor; R15-R18 all failed
// to beat it). q,k MUST stay fp32-VALU (R11-R14: MFMA split fails at absmax
// 1.0-1.375 via denominator amplification).
// ---------------------------------------------------------------------------
__global__ __launch_bounds__(256) void gemm1_f32(
    const float* __restrict__ A, const float* __restrict__ B,
    float* __restrict__ C) {
  __shared__ float As[32][132];  // [k][m]
  __shared__ float Bs[32][68];   // [k][n]
  const int tid = threadIdx.x;
  const int tx = tid & 15, ty = tid >> 4;
  const int bm = blockIdx.y * 128, bn = blockIdx.x * 64;
  const int rowA = tid & 127, c4a = tid >> 7;  // 0..1
  const int rowB = tid & 63,  c4b = tid >> 6;  // 0..3

  float acc[8][4] = {};

  for (int k0 = 0; k0 < 512; k0 += 32) {
#pragma unroll
    for (int p = 0; p < 4; ++p) {
      int c4 = c4a + 2 * p;
      float4 fa = *(const float4*)(A + (size_t)(bm + rowA) * 512 + k0 + c4 * 4);
      As[c4 * 4 + 0][rowA] = fa.x; As[c4 * 4 + 1][rowA] = fa.y;
      As[c4 * 4 + 2][rowA] = fa.z; As[c4 * 4 + 3][rowA] = fa.w;
    }
#pragma unroll
    for (int p = 0; p < 2; ++p) {
      int c4 = c4b + 4 * p;
      float4 fb = *(const float4*)(B + (size_t)(bn + rowB) * 512 + k0 + c4 * 4);
      Bs[c4 * 4 + 0][rowB] = fb.x; Bs[c4 * 4 + 1][rowB] = fb.y;
      Bs[c4 * 4 + 2][rowB] = fb.z; Bs[c4 * 4 + 3][rowB] = fb.w;
    }
    __syncthreads();
#pragma unroll
    for (int kk = 0; kk < 32; ++kk) {
      float a[8], b[4];
      *(float4*)&a[0] = *(const float4*)&As[kk][ty * 8];
      *(float4*)&a[4] = *(const float4*)&As[kk][ty * 8 + 4];
      *(float4*)&b[0] = *(const float4*)&Bs[kk][tx * 4];
#pragma unroll
      for (int i = 0; i < 8; ++i)
#pragma unroll
        for (int j = 0; j < 4; ++j) acc[i][j] += a[i] * b[j];
    }
    __syncthreads();
  }

#pragma unroll
  for (int i = 0; i < 8; ++i) {
    size_t row = bm + ty * 8 + i;
    float4 r;
    r.x = acc[i][0]; r.y = acc[i][1]; r.z = acc[i][2]; r.w = acc[i][3];
    *(float4*)(C + row * (size_t)TQKV + bn + tx * 4) = r;
  }
}

// ---------------------------------------------------------------------------
// ONE split dispatch for x, w_qkv v-rows, and w_out (R23, neutral-or-better).
// Block ranges: [0,2048) x ; [2048,2304) wv ; [2304,2560) w_out.
// ---------------------------------------------------------------------------
__global__ __launch_bounds__(256) void split_all(
    const float* __restrict__ x, const float* __restrict__ wv,
    const float* __restrict__ wout,
    _Float16* __restrict__ xh, _Float16* __restrict__ xl,
    _Float16* __restrict__ wvh, _Float16* __restrict__ wvl,
    _Float16* __restrict__ woh, _Float16* __restrict__ wol) {
  const int blk = blockIdx.x;
  const float* s;
  _Float16 *hi, *lo;
  int i;
  if (blk < 2048) {
    s = x; hi = xh; lo = xl; i = blk * 256 + threadIdx.x;
  } else if (blk < 2304) {
    s = wv; hi = wvh; lo = wvl; i = (blk - 2048) * 256 + threadIdx.x;
  } else {
    s = wout; hi = woh; lo = wol; i = (blk - 2304) * 256 + threadIdx.x;
  }
  float4 a = ((const float4*)s)[i];
  half4 h, l;
  float av[4] = {a.x, a.y, a.z, a.w};
#pragma unroll
  for (int j = 0; j < 4; ++j) {
    _Float16 hh = (_Float16)av[j];
    h[j] = hh;
    l[j] = (_Float16)((av[j] - (float)hh) * 2048.0f);
  }
  ((half4*)hi)[i] = h;
  ((half4*)lo)[i] = l;
}

// ---------------------------------------------------------------------------
// 2-term split-f16 NT GEMM via MFMA (proven). vGEMM and GEMM2.
// ---------------------------------------------------------------------------
__global__ __launch_bounds__(256) void gemm_split_nt(
    const _Float16* __restrict__ Ah, const _Float16* __restrict__ Al,
    const _Float16* __restrict__ Bh, const _Float16* __restrict__ Bl,
    const float* __restrict__ bias, float* __restrict__ C,
    int Ndim, int Kd) {
  constexpr int BM = 128, BN = 64, BK = 32;
  __shared__ _Float16 lds[(2 * BM + 2 * BN) * BK];  // 24 KB
  constexpr int AHo = 0;
  constexpr int ALo = BM * BK;
  constexpr int BHo = 2 * BM * BK;
  constexpr int BLo = 2 * BM * BK + BN * BK;

  const int tid = threadIdx.x;
  const int wave = tid >> 6, lane = tid & 63;
  const int lq = lane >> 4, lm = lane & 15;
  const int bm = blockIdx.y * BM, bn = blockIdx.x * BN;

  f32x4 acc[2][4] = {};
  f32x4 corr[2][4] = {};

  const int nsteps = Kd >> 5;
  for (int ks = 0; ks < nsteps; ++ks) {
    const int k0 = ks * BK;
    for (int idx = wave; idx < 24; idx += 4) {
      int t, j;
      if (idx < 8)       { t = 0; j = idx; }
      else if (idx < 16) { t = 1; j = idx - 8; }
      else if (idx < 20) { t = 2; j = idx - 16; }
      else               { t = 3; j = idx - 20; }
      const int row = j * 16 + (lane >> 2);
      const _Float16* g;
      _Float16* l;
      if (t == 0)      { g = Ah + (size_t)(bm + row) * Kd; l = lds + AHo + j * 16 * BK; }
      else if (t == 1) { g = Al + (size_t)(bm + row) * Kd; l = lds + ALo + j * 16 * BK; }
      else if (t == 2) { g = Bh + (size_t)(bn + row) * Kd; l = lds + BHo + j * 16 * BK; }
      else             { g = Bl + (size_t)(bn + row) * Kd; l = lds + BLo + j * 16 * BK; }
      g += k0 + (lane & 3) * 8;
      __builtin_amdgcn_global_load_lds(AS1(g), AS3(l), 16, 0, 0);
    }
    __syncthreads();

    half8 ahf[2], alf[2], bhf[4], blf[4];
    const int mwo = wave * 32;
#pragma unroll
    for (int fi = 0; fi < 2; ++fi) {
      ahf[fi] = *(const half8*)&lds[AHo + (mwo + fi * 16 + lm) * BK + lq * 8];
      alf[fi] = *(const half8*)&lds[ALo + (mwo + fi * 16 + lm) * BK + lq * 8];
    }
#pragma unroll
    for (int fj = 0; fj < 4; ++fj) {
      bhf[fj] = *(const half8*)&lds[BHo + (fj * 16 + lm) * BK + lq * 8];
      blf[fj] = *(const half8*)&lds[BLo + (fj * 16 + lm) * BK + lq * 8];
    }
#pragma unroll
    for (int fi = 0; fi < 2; ++fi)
#pragma unroll
      for (int fj = 0; fj < 4; ++fj) {
        acc[fi][fj] = __builtin_amdgcn_mfma_f32_16x16x32_f16(
            ahf[fi], bhf[fj], acc[fi][fj], 0, 0, 0);
        corr[fi][fj] = __builtin_amdgcn_mfma_f32_16x16x32_f16(
            ahf[fi], blf[fj], corr[fi][fj], 0, 0, 0);
        corr[fi][fj] = __builtin_amdgcn_mfma_f32_16x16x32_f16(
            alf[fi], bhf[fj], corr[fi][fj], 0, 0, 0);
      }
    __syncthreads();
  }

#pragma unroll
  for (int fi = 0; fi < 2; ++fi) {
    const int m0 = bm + wave * 32 + fi * 16 + lq * 4;
#pragma unroll
    for (int fj = 0; fj < 4; ++fj) {
      const int n = bn + fj * 16 + lm;
      const float bb = bias ? bias[n] : 0.f;
      f32x4 v = acc[fi][fj];
      f32x4 cv = corr[fi][fj];
#pragma unroll
      for (int r = 0; r < 4; ++r)
        C[(size_t)(m0 + r) * Ndim + n] = v[r] + cv[r] * (1.0f / 2048.0f) + bb;
    }
  }
}

// ---------------------------------------------------------------------------
// Pass 1, R24: LN(k,v) in LDS + S_c sums. NO qkv writeback (16 MB deleted) —
// chunk_attn re-applies the identical LN on the same raw data (bit-identical
// values). Everything else R0-exact.
// ---------------------------------------------------------------------------
__global__ __launch_bounds__(256) void chunk_sums_ln(
    const float* __restrict__ qkv, const float* __restrict__ lnk_w,
    const float* __restrict__ lnk_b, const float* __restrict__ lnv_w,
    const float* __restrict__ lnv_b, float* __restrict__ cbuf) {
  int blk = blockIdx.x;
  int c = blk % NCH;
  int bh = blk / NCH;
  int h = bh % Hh, b = bh / Hh;
  __shared__ float Ks[CH][68];
  __shared__ float Vs[CH][68];
  int tid = threadIdx.x;
  const float* base = qkv + (size_t)(b * Nn + c * CH) * TQKV + h * Dd;
  for (int i = tid; i < CH * 16; i += 256) {
    int row = i >> 4, c4 = i & 15;
    *(float4*)&Ks[row][c4 * 4] =
        *(const float4*)(base + (size_t)row * TQKV + INNER + c4 * 4);
    *(float4*)&Vs[row][c4 * 4] =
        *(const float4*)(base + (size_t)row * TQKV + 2 * INNER + c4 * 4);
  }
  __syncthreads();

  if (tid < 128) {
    bool isv = tid >= 64;
    int row = tid & 63;
    float* R = isv ? &Vs[row][0] : &Ks[row][0];
    float s = 0.f, s2 = 0.f;
#pragma unroll
    for (int j = 0; j < 64; j += 4) {
      float4 v = *(const float4*)&R[j];
      s += v.x + v.y + v.z + v.w;
      s2 += v.x * v.x + v.y * v.y + v.z * v.z + v.w * v.w;
    }
    float mean = s * (1.f / 64.f);
    float var = s2 * (1.f / 64.f) - mean * mean;
    float inv = 1.0f / sqrtf(var + EPSF);
    const float* w = isv ? lnv_w : lnk_w;
    const float* bb = isv ? lnv_b : lnk_b;
#pragma unroll
    for (int j = 0; j < 64; ++j)
      R[j] = (R[j] - mean) * inv * w[h * Dd + j] + bb[h * Dd + j];
  }
  __syncthreads();

  int d0 = (tid >> 4) * 4, e0 = (tid & 15) * 4;
  float acc[4][4] = {};
  float kc[4] = {0.f, 0.f, 0.f, 0.f};
  for (int n = 0; n < CH; ++n) {
    float4 kv = *(const float4*)&Ks[n][d0];
    float4 vv = *(const float4*)&Vs[n][e0];
    float ka[4] = {kv.x, kv.y, kv.z, kv.w};
    float va[4] = {vv.x, vv.y, vv.z, vv.w};
#pragma unroll
    for (int i = 0; i < 4; ++i)
#pragma unroll
      for (int j = 0; j < 4; ++j) acc[i][j] += ka[i] * va[j];
    if (e0 == 0) {
#pragma unroll
      for (int i = 0; i < 4; ++i) kc[i] += ka[i];
    }
  }
  float* out = cbuf + (size_t)blk * CSZ;
#pragma unroll
  for (int i = 0; i < 4; ++i) {
    float4 r;
    r.x = acc[i][0]; r.y = acc[i][1]; r.z = acc[i][2]; r.w = acc[i][3];
    *(float4*)(out + (size_t)(d0 + i) * Dd + e0) = r;
  }
  if (e0 == 0) {
#pragma unroll
    for (int i = 0; i < 4; ++i) out[Dd * Dd + d0 + i] = kc[i];
  }
}

// ---------------------------------------------------------------------------
// Pass 2, R24: BATCHED prefix — load all 32 chunk values into registers
// (independent addresses -> one overlapped vmcnt window instead of 32
// serial HBM round-trips), scan in registers (same adds, same order =>
// bit-identical), batch store.
// ---------------------------------------------------------------------------
__global__ __launch_bounds__(256) void chunk_prefix(float* __restrict__ cbuf) {
  int bh = blockIdx.y;
  int i = blockIdx.x * 256 + threadIdx.x;
  if (i >= CSZ) return;
  float* p = cbuf + (size_t)bh * NCH * CSZ + i;
  float v[NCH];
#pragma unroll
  for (int c = 0; c < NCH; ++c) v[c] = p[(size_t)c * CSZ];
  float carry = 0.f;
#pragma unroll
  for (int c = 0; c < NCH; ++c) {
    float t = v[c];
    v[c] = carry;
    carry += t;
  }
#pragma unroll
  for (int c = 0; c < NCH; ++c) p[(size_t)c * CSZ] = v[c];
}

// ---------------------------------------------------------------------------
// Pass 3, R24: attn now applies LN itself (same raw inputs, same expression
// trees, same j-ascending accumulation as chunk_sums_ln => bit-identical
// LN'd values). K is LN'd column-wise in its transposed [d][m] layout
// (per-instruction accesses are consecutive-m => conflict-free).
// Everything downstream R0-exact.
// ---------------------------------------------------------------------------
__global__ __launch_bounds__(256) void chunk_attn(
    const float* __restrict__ qkv, const float* __restrict__ cbuf,
    const float* __restrict__ lnk_w, const float* __restrict__ lnk_b,
    const float* __restrict__ lnv_w, const float* __restrict__ lnv_b,
    _Float16* __restrict__ atth, _Float16* __restrict__ attl) {
  int blk = blockIdx.x;
  int c = blk % NCH;
  int bh = blk / NCH;
  int h = bh % Hh, b = bh / Hh;
  __shared__ float Qs[64][68];   // [d][n]
  __shared__ float Ks[64][68];   // [d][m]; later reused as Ps[m][n]
  __shared__ float Vs[64][68];   // [m][e]
  __shared__ float Ss[64][68];   // [d][e]
  __shared__ float kcs[64];
  __shared__ float rs[64][17];
  __shared__ float denomS[64];
  float (*Ps)[68] = Ks;          // overlay

  int tid = threadIdx.x;
  int tx = tid & 15, ty = tid >> 4;
  const float* base = qkv + (size_t)(b * Nn + c * CH) * TQKV + h * Dd;
  for (int i = tid; i < CH * 16; i += 256) {
    int row = i >> 4, c4 = i & 15;
    float4 fq = *(const float4*)(base + (size_t)row * TQKV + c4 * 4);
    Qs[c4 * 4 + 0][row] = fq.x; Qs[c4 * 4 + 1][row] = fq.y;
    Qs[c4 * 4 + 2][row] = fq.z; Qs[c4 * 4 + 3][row] = fq.w;
    float4 fk = *(const float4*)(base + (size_t)row * TQKV + INNER + c4 * 4);
    Ks[c4 * 4 + 0][row] = fk.x; Ks[c4 * 4 + 1][row] = fk.y;
    Ks[c4 * 4 + 2][row] = fk.z; Ks[c4 * 4 + 3][row] = fk.w;
    float4 fv = *(const float4*)(base + (size_t)row * TQKV + 2 * INNER + c4 * 4);
    *(float4*)&Vs[row][c4 * 4] = fv;
  }
  const float* sp = cbuf + (size_t)blk * CSZ;
  for (int i = tid; i < 1024; i += 256) {
    int row = i >> 4;
    *(float4*)&Ss[row][(i & 15) * 4] = *(const float4*)(sp + (size_t)i * 4);
  }
  if (tid < 16) {
    float4 f = *(const float4*)(sp + Dd * Dd + tid * 4);
    kcs[tid * 4 + 0] = f.x; kcs[tid * 4 + 1] = f.y;
    kcs[tid * 4 + 2] = f.z; kcs[tid * 4 + 3] = f.w;
  }
  __syncthreads();

  // --- LN recompute (bit-identical to chunk_sums_ln's LN) ---
  if (tid < 64) {
    // K column m = tid in transposed layout Ks[d][m]
    int m = tid;
    float s = 0.f, s2 = 0.f;
#pragma unroll
    for (int j = 0; j < 64; j += 4) {
      float a0 = Ks[j + 0][m], a1 = Ks[j + 1][m];
      float a2 = Ks[j + 2][m], a3 = Ks[j + 3][m];
      s += a0 + a1 + a2 + a3;
      s2 += a0 * a0 + a1 * a1 + a2 * a2 + a3 * a3;
    }
    float mean = s * (1.f / 64.f);
    float var = s2 * (1.f / 64.f) - mean * mean;
    float inv = 1.0f / sqrtf(var + EPSF);
#pragma unroll
    for (int j = 0; j < 64; ++j)
      Ks[j][m] = (Ks[j][m] - mean) * inv * lnk_w[h * Dd + j] + lnk_b[h * Dd + j];
  } else if (tid < 128) {
    // V row (float4 path, verbatim from chunk_sums_ln)
    int row = tid & 63;
    float* R = &Vs[row][0];
    float s = 0.f, s2 = 0.f;
#pragma unroll
    for (int j = 0; j < 64; j += 4) {
      float4 v = *(const float4*)&R[j];
      s += v.x + v.y + v.z + v.w;
      s2 += v.x * v.x + v.y * v.y + v.z * v.z + v.w * v.w;
    }
    float mean = s * (1.f / 64.f);
    float var = s2 * (1.f / 64.f) - mean * mean;
    float inv = 1.0f / sqrtf(var + EPSF);
#pragma unroll
    for (int j = 0; j < 64; ++j)
      R[j] = (R[j] - mean) * inv * lnv_w[h * Dd + j] + lnv_b[h * Dd + j];
  }
  __syncthreads();

  // P = Q K^T into registers
  float accP[4][4] = {};
  for (int kk = 0; kk < 64; ++kk) {
    float4 qa = *(const float4*)&Qs[kk][ty * 4];
    float4 kb = *(const float4*)&Ks[kk][tx * 4];
    float qv[4] = {qa.x, qa.y, qa.z, qa.w};
    float kv[4] = {kb.x, kb.y, kb.z, kb.w};
#pragma unroll
    for (int i = 0; i < 4; ++i)
#pragma unroll
      for (int j = 0; j < 4; ++j) accP[i][j] += qv[i] * kv[j];
  }
  __syncthreads();  // Ks reads done before Ps overlay is written

#pragma unroll
  for (int i = 0; i < 4; ++i) {
    int n = ty * 4 + i;
    float rsum = 0.f;
#pragma unroll
    for (int j = 0; j < 4; ++j) {
      int m = tx * 4 + j;
      float p = (m <= n) ? accP[i][j] : 0.f;
      Ps[m][n] = p;
      rsum += p;
    }
    rs[n][tx] = rsum;
  }
  __syncthreads();

  // O = Q * S_prefix; denom
  float accO[4][4] = {};
  for (int d = 0; d < 64; ++d) {
    float4 qa = *(const float4*)&Qs[d][ty * 4];
    float4 sb = *(const float4*)&Ss[d][tx * 4];
    float qv[4] = {qa.x, qa.y, qa.z, qa.w};
    float sv[4] = {sb.x, sb.y, sb.z, sb.w};
#pragma unroll
    for (int i = 0; i < 4; ++i)
#pragma unroll
      for (int j = 0; j < 4; ++j) accO[i][j] += qv[i] * sv[j];
  }
  if (tid < 64) {
    int n = tid;
    float qkc = 0.f, qs = 0.f;
    for (int d = 0; d < 64; ++d) {
      float q = Qs[d][n];
      qkc += q * kcs[d];
      qs += q;
    }
    float rsum = 0.f;
#pragma unroll
    for (int t2 = 0; t2 < 16; ++t2) rsum += rs[n][t2];
    denomS[n] = qkc + rsum + EPSF * qs;
  }
  __syncthreads();

  // O += P_masked * V
  for (int m = 0; m < 64; ++m) {
    float4 pa = *(const float4*)&Ps[m][ty * 4];
    float4 vb = *(const float4*)&Vs[m][tx * 4];
    float pv[4] = {pa.x, pa.y, pa.z, pa.w};
    float vv[4] = {vb.x, vb.y, vb.z, vb.w};
#pragma unroll
    for (int i = 0; i < 4; ++i)
#pragma unroll
      for (int j = 0; j < 4; ++j) accO[i][j] += pv[i] * vv[j];
  }

  size_t obase = (size_t)(b * Nn + c * CH) * INNER + h * Dd;
#pragma unroll
  for (int i = 0; i < 4; ++i) {
    int n = ty * 4 + i;
    float dinv = 1.0f / denomS[n];
    float scale = dinv * (1.0f / (float)Nn);
    half4 hv, lv;
#pragma unroll
    for (int j = 0; j < 4; ++j) {
      float o = accO[i][j] * scale;
      _Float16 hh = (_Float16)o;
      hv[j] = hh;
      lv[j] = (_Float16)((o - (float)hh) * 2048.0f);
    }
    *(half4*)(atth + obase + (size_t)n * INNER + tx * 4) = hv;
    *(half4*)(attl + obase + (size_t)n * INNER + tx * 4) = lv;
  }
}

// ---------------------------------------------------------------------------
extern "C" void kernel_launch(void* const* d_in, const int* in_sizes, int n_in,
                              void* d_out, int out_size, void* d_ws,
                              size_t ws_size, hipStream_t stream) {
  const float* x     = (const float*)d_in[0];
  const float* w_qkv = (const float*)d_in[1];
  const float* lnk_w = (const float*)d_in[2];
  const float* lnk_b = (const float*)d_in[3];
  const float* lnv_w = (const float*)d_in[4];
  const float* lnv_b = (const float*)d_in[5];
  const float* w_out = (const float*)d_in[6];
  const float* b_out = (const float*)d_in[7];
  float* out = (float*)d_out;

  // Workspace layout (~52.56 MB, the exact R0-proven layout):
  float* qkv  = (float*)d_ws;                      // 4096*1536 fp32
  float* cbuf = qkv + (size_t)Mm * TQKV;           // 512*4160 fp32
  _Float16* atth = (_Float16*)(cbuf + (size_t)Bb * Hh * NCH * CSZ);
  _Float16* attl = atth + (size_t)Mm * INNER;
  _Float16* woh  = attl + (size_t)Mm * INNER;
  _Float16* wol  = woh + (size_t)INNER * 512;
  _Float16* xh   = wol + (size_t)INNER * 512;      // x split 4096x512
  _Float16* xl   = xh + (size_t)Mm * 512;
  _Float16* wvh  = xl + (size_t)Mm * 512;          // w_qkv v-rows split 512x512
  _Float16* wvl  = wvh + (size_t)INNER * 512;

  // 1a. ONE split dispatch: x + w_qkv v-rows + w_out
  split_all<<<2560, 256, 0, stream>>>(
      x, w_qkv + (size_t)1024 * 512, w_out,
      xh, xl, wvh, wvl, woh, wol);

  // 1b. GEMM1-qk (fp32 VALU, N=1024): R0-exact (~70 us proven)
  gemm1_f32<<<dim3(1024 / 64, Mm / 128), 256, 0, stream>>>(x, w_qkv, qkv);

  // 1c. GEMM1-v (2-term split MFMA, N=512): writes qkv cols 1024..1535
  gemm_split_nt<<<dim3(512 / 64, Mm / 128), 256, 0, stream>>>(
      xh, xl, wvh, wvl, nullptr, qkv + 1024, TQKV, 512);

  // 2. LN(k,v) + per-chunk K^T V + colsum(K) — no qkv writeback
  chunk_sums_ln<<<Bb * Hh * NCH, 256, 0, stream>>>(
      qkv, lnk_w, lnk_b, lnv_w, lnv_b, cbuf);

  // 3. Exclusive prefix over chunks — batched loads/stores
  chunk_prefix<<<dim3((CSZ + 255) / 256, Bb * Hh), 256, 0, stream>>>(cbuf);

  // 4. Per-chunk attention (applies LN itself) -> attn split f16
  chunk_attn<<<Bb * Hh * NCH, 256, 0, stream>>>(
      qkv, cbuf, lnk_w, lnk_b, lnv_w, lnv_b, atth, attl);

  // 5. Output GEMM: out = attn * w_out^T + b_out (2-term split MFMA)
  gemm_split_nt<<<dim3(INNER / 64, Mm / 128), 256, 0, stream>>>(
      atth, attl, woh, wol, b_out, out, INNER, 512);
}

// Round 16
// 231.769 us; speedup vs baseline: 1.7663x; 1.0038x over previous
//
#include <hip/hip_runtime.h>

// Problem constants
constexpr int Bb   = 2;
constexpr int Nn   = 2048;
constexpr int Hh   = 8;
constexpr int Dd   = 64;
constexpr int Mm   = Bb * Nn;      // 4096 rows
constexpr int TQKV = 1536;         // 3 * H * D
constexpr int INNER = Hh * Dd;     // 512
constexpr int CH   = 64;           // chunk length
constexpr int NCH  = Nn / CH;      // 32 chunks per (b,h)
constexpr int CSZ  = Dd * Dd + Dd; // 4160 floats per chunk record (S + kc)
constexpr float EPSF = 1e-7f;

typedef _Float16 half8 __attribute__((ext_vector_type(8)));
typedef _Float16 half4 __attribute__((ext_vector_type(4)));
typedef float f32x4 __attribute__((ext_vector_type(4)));

#define AS1(p) ((const __attribute__((address_space(1))) unsigned int*)(p))
#define AS3(p) ((__attribute__((address_space(3))) unsigned int*)(p))

// ---------------------------------------------------------------------------
// GEMM1-qk (fp32 VALU): R0-EXACT (~70 us proven floor). q,k MUST stay
// fp32-VALU (R11-R14: MFMA split fails via denominator amplification).
// ---------------------------------------------------------------------------
__global__ __launch_bounds__(256) void gemm1_f32(
    const float* __restrict__ A, const float* __restrict__ B,
    float* __restrict__ C) {
  __shared__ float As[32][132];  // [k][m]
  __shared__ float Bs[32][68];   // [k][n]
  const int tid = threadIdx.x;
  const int tx = tid & 15, ty = tid >> 4;
  const int bm = blockIdx.y * 128, bn = blockIdx.x * 64;
  const int rowA = tid & 127, c4a = tid >> 7;  // 0..1
  const int rowB = tid & 63,  c4b = tid >> 6;  // 0..3

  float acc[8][4] = {};

  for (int k0 = 0; k0 < 512; k0 += 32) {
#pragma unroll
    for (int p = 0; p < 4; ++p) {
      int c4 = c4a + 2 * p;
      float4 fa = *(const float4*)(A + (size_t)(bm + rowA) * 512 + k0 + c4 * 4);
      As[c4 * 4 + 0][rowA] = fa.x; As[c4 * 4 + 1][rowA] = fa.y;
      As[c4 * 4 + 2][rowA] = fa.z; As[c4 * 4 + 3][rowA] = fa.w;
    }
#pragma unroll
    for (int p = 0; p < 2; ++p) {
      int c4 = c4b + 4 * p;
      float4 fb = *(const float4*)(B + (size_t)(bn + rowB) * 512 + k0 + c4 * 4);
      Bs[c4 * 4 + 0][rowB] = fb.x; Bs[c4 * 4 + 1][rowB] = fb.y;
      Bs[c4 * 4 + 2][rowB] = fb.z; Bs[c4 * 4 + 3][rowB] = fb.w;
    }
    __syncthreads();
#pragma unroll
    for (int kk = 0; kk < 32; ++kk) {
      float a[8], b[4];
      *(float4*)&a[0] = *(const float4*)&As[kk][ty * 8];
      *(float4*)&a[4] = *(const float4*)&As[kk][ty * 8 + 4];
      *(float4*)&b[0] = *(const float4*)&Bs[kk][tx * 4];
#pragma unroll
      for (int i = 0; i < 8; ++i)
#pragma unroll
        for (int j = 0; j < 4; ++j) acc[i][j] += a[i] * b[j];
    }
    __syncthreads();
  }

#pragma unroll
  for (int i = 0; i < 8; ++i) {
    size_t row = bm + ty * 8 + i;
    float4 r;
    r.x = acc[i][0]; r.y = acc[i][1]; r.z = acc[i][2]; r.w = acc[i][3];
    *(float4*)(C + row * (size_t)TQKV + bn + tx * 4) = r;
  }
}

// ---------------------------------------------------------------------------
// ONE split dispatch for x, w_qkv v-rows, and w_out.
// Block ranges: [0,2048) x ; [2048,2304) wv ; [2304,2560) w_out.
// ---------------------------------------------------------------------------
__global__ __launch_bounds__(256) void split_all(
    const float* __restrict__ x, const float* __restrict__ wv,
    const float* __restrict__ wout,
    _Float16* __restrict__ xh, _Float16* __restrict__ xl,
    _Float16* __restrict__ wvh, _Float16* __restrict__ wvl,
    _Float16* __restrict__ woh, _Float16* __restrict__ wol) {
  const int blk = blockIdx.x;
  const float* s;
  _Float16 *hi, *lo;
  int i;
  if (blk < 2048) {
    s = x; hi = xh; lo = xl; i = blk * 256 + threadIdx.x;
  } else if (blk < 2304) {
    s = wv; hi = wvh; lo = wvl; i = (blk - 2048) * 256 + threadIdx.x;
  } else {
    s = wout; hi = woh; lo = wol; i = (blk - 2304) * 256 + threadIdx.x;
  }
  float4 a = ((const float4*)s)[i];
  half4 h, l;
  float av[4] = {a.x, a.y, a.z, a.w};
#pragma unroll
  for (int j = 0; j < 4; ++j) {
    _Float16 hh = (_Float16)av[j];
    h[j] = hh;
    l[j] = (_Float16)((av[j] - (float)hh) * 2048.0f);
  }
  ((half4*)hi)[i] = h;
  ((half4*)lo)[i] = l;
}

// ---------------------------------------------------------------------------
// 2-term split-f16 NT GEMM via MFMA (proven). vGEMM and GEMM2.
// ---------------------------------------------------------------------------
__global__ __launch_bounds__(256) void gemm_split_nt(
    const _Float16* __restrict__ Ah, const _Float16* __restrict__ Al,
    const _Float16* __restrict__ Bh, const _Float16* __restrict__ Bl,
    const float* __restrict__ bias, float* __restrict__ C,
    int Ndim, int Kd) {
  constexpr int BM = 128, BN = 64, BK = 32;
  __shared__ _Float16 lds[(2 * BM + 2 * BN) * BK];  // 24 KB
  constexpr int AHo = 0;
  constexpr int ALo = BM * BK;
  constexpr int BHo = 2 * BM * BK;
  constexpr int BLo = 2 * BM * BK + BN * BK;

  const int tid = threadIdx.x;
  const int wave = tid >> 6, lane = tid & 63;
  const int lq = lane >> 4, lm = lane & 15;
  const int bm = blockIdx.y * BM, bn = blockIdx.x * BN;

  f32x4 acc[2][4] = {};
  f32x4 corr[2][4] = {};

  const int nsteps = Kd >> 5;
  for (int ks = 0; ks < nsteps; ++ks) {
    const int k0 = ks * BK;
    for (int idx = wave; idx < 24; idx += 4) {
      int t, j;
      if (idx < 8)       { t = 0; j = idx; }
      else if (idx < 16) { t = 1; j = idx - 8; }
      else if (idx < 20) { t = 2; j = idx - 16; }
      else               { t = 3; j = idx - 20; }
      const int row = j * 16 + (lane >> 2);
      const _Float16* g;
      _Float16* l;
      if (t == 0)      { g = Ah + (size_t)(bm + row) * Kd; l = lds + AHo + j * 16 * BK; }
      else if (t == 1) { g = Al + (size_t)(bm + row) * Kd; l = lds + ALo + j * 16 * BK; }
      else if (t == 2) { g = Bh + (size_t)(bn + row) * Kd; l = lds + BHo + j * 16 * BK; }
      else             { g = Bl + (size_t)(bn + row) * Kd; l = lds + BLo + j * 16 * BK; }
      g += k0 + (lane & 3) * 8;
      __builtin_amdgcn_global_load_lds(AS1(g), AS3(l), 16, 0, 0);
    }
    __syncthreads();

    half8 ahf[2], alf[2], bhf[4], blf[4];
    const int mwo = wave * 32;
#pragma unroll
    for (int fi = 0; fi < 2; ++fi) {
      ahf[fi] = *(const half8*)&lds[AHo + (mwo + fi * 16 + lm) * BK + lq * 8];
      alf[fi] = *(const half8*)&lds[ALo + (mwo + fi * 16 + lm) * BK + lq * 8];
    }
#pragma unroll
    for (int fj = 0; fj < 4; ++fj) {
      bhf[fj] = *(const half8*)&lds[BHo + (fj * 16 + lm) * BK + lq * 8];
      blf[fj] = *(const half8*)&lds[BLo + (fj * 16 + lm) * BK + lq * 8];
    }
#pragma unroll
    for (int fi = 0; fi < 2; ++fi)
#pragma unroll
      for (int fj = 0; fj < 4; ++fj) {
        acc[fi][fj] = __builtin_amdgcn_mfma_f32_16x16x32_f16(
            ahf[fi], bhf[fj], acc[fi][fj], 0, 0, 0);
        corr[fi][fj] = __builtin_amdgcn_mfma_f32_16x16x32_f16(
            ahf[fi], blf[fj], corr[fi][fj], 0, 0, 0);
        corr[fi][fj] = __builtin_amdgcn_mfma_f32_16x16x32_f16(
            alf[fi], bhf[fj], corr[fi][fj], 0, 0, 0);
      }
    __syncthreads();
  }

#pragma unroll
  for (int fi = 0; fi < 2; ++fi) {
    const int m0 = bm + wave * 32 + fi * 16 + lq * 4;
#pragma unroll
    for (int fj = 0; fj < 4; ++fj) {
      const int n = bn + fj * 16 + lm;
      const float bb = bias ? bias[n] : 0.f;
      f32x4 v = acc[fi][fj];
      f32x4 cv = corr[fi][fj];
#pragma unroll
      for (int r = 0; r < 4; ++r)
        C[(size_t)(m0 + r) * Ndim + n] = v[r] + cv[r] * (1.0f / 2048.0f) + bb;
    }
  }
}

// ---------------------------------------------------------------------------
// Pass 1, R25: LN(k,v) + S_c sums; NO qkv writeback. The 64-iter K^T V
// accumulation loop gets #pragma unroll 8 — gemm1's inner loop was always
// fully unrolled, but the tail loops never were (rolled loops expose full
// LDS latency per iteration at 8 waves/CU => the measured 8% VALUBusy).
// Unrolling preserves n-ascending per-accumulator order => bit-identical.
// ---------------------------------------------------------------------------
__global__ __launch_bounds__(256) void chunk_sums_ln(
    const float* __restrict__ qkv, const float* __restrict__ lnk_w,
    const float* __restrict__ lnk_b, const float* __restrict__ lnv_w,
    const float* __restrict__ lnv_b, float* __restrict__ cbuf) {
  int blk = blockIdx.x;
  int c = blk % NCH;
  int bh = blk / NCH;
  int h = bh % Hh, b = bh / Hh;
  __shared__ float Ks[CH][68];
  __shared__ float Vs[CH][68];
  int tid = threadIdx.x;
  const float* base = qkv + (size_t)(b * Nn + c * CH) * TQKV + h * Dd;
  for (int i = tid; i < CH * 16; i += 256) {
    int row = i >> 4, c4 = i & 15;
    *(float4*)&Ks[row][c4 * 4] =
        *(const float4*)(base + (size_t)row * TQKV + INNER + c4 * 4);
    *(float4*)&Vs[row][c4 * 4] =
        *(const float4*)(base + (size_t)row * TQKV + 2 * INNER + c4 * 4);
  }
  __syncthreads();

  if (tid < 128) {
    bool isv = tid >= 64;
    int row = tid & 63;
    float* R = isv ? &Vs[row][0] : &Ks[row][0];
    float s = 0.f, s2 = 0.f;
#pragma unroll
    for (int j = 0; j < 64; j += 4) {
      float4 v = *(const float4*)&R[j];
      s += v.x + v.y + v.z + v.w;
      s2 += v.x * v.x + v.y * v.y + v.z * v.z + v.w * v.w;
    }
    float mean = s * (1.f / 64.f);
    float var = s2 * (1.f / 64.f) - mean * mean;
    float inv = 1.0f / sqrtf(var + EPSF);
    const float* w = isv ? lnv_w : lnk_w;
    const float* bb = isv ? lnv_b : lnk_b;
#pragma unroll
    for (int j = 0; j < 64; ++j)
      R[j] = (R[j] - mean) * inv * w[h * Dd + j] + bb[h * Dd + j];
  }
  __syncthreads();

  int d0 = (tid >> 4) * 4, e0 = (tid & 15) * 4;
  float acc[4][4] = {};
  float kc[4] = {0.f, 0.f, 0.f, 0.f};
#pragma unroll 8
  for (int n = 0; n < CH; ++n) {
    float4 kv = *(const float4*)&Ks[n][d0];
    float4 vv = *(const float4*)&Vs[n][e0];
    float ka[4] = {kv.x, kv.y, kv.z, kv.w};
    float va[4] = {vv.x, vv.y, vv.z, vv.w};
#pragma unroll
    for (int i = 0; i < 4; ++i)
#pragma unroll
      for (int j = 0; j < 4; ++j) acc[i][j] += ka[i] * va[j];
    if (e0 == 0) {
#pragma unroll
      for (int i = 0; i < 4; ++i) kc[i] += ka[i];
    }
  }
  float* out = cbuf + (size_t)blk * CSZ;
#pragma unroll
  for (int i = 0; i < 4; ++i) {
    float4 r;
    r.x = acc[i][0]; r.y = acc[i][1]; r.z = acc[i][2]; r.w = acc[i][3];
    *(float4*)(out + (size_t)(d0 + i) * Dd + e0) = r;
  }
  if (e0 == 0) {
#pragma unroll
    for (int i = 0; i < 4; ++i) out[Dd * Dd + d0 + i] = kc[i];
  }
}

// ---------------------------------------------------------------------------
// Pass 2: BATCHED prefix (R24).
// ---------------------------------------------------------------------------
__global__ __launch_bounds__(256) void chunk_prefix(float* __restrict__ cbuf) {
  int bh = blockIdx.y;
  int i = blockIdx.x * 256 + threadIdx.x;
  if (i >= CSZ) return;
  float* p = cbuf + (size_t)bh * NCH * CSZ + i;
  float v[NCH];
#pragma unroll
  for (int c = 0; c < NCH; ++c) v[c] = p[(size_t)c * CSZ];
  float carry = 0.f;
#pragma unroll
  for (int c = 0; c < NCH; ++c) {
    float t = v[c];
    v[c] = carry;
    carry += t;
  }
#pragma unroll
  for (int c = 0; c < NCH; ++c) p[(size_t)c * CSZ] = v[c];
}

// ---------------------------------------------------------------------------
// Pass 3, R25: attn with LN-recompute (R24, bit-identical-value). The four
// 64-iter loops (P, Q*S, denom, P*V) get #pragma unroll 8 — batches LDS
// reads in-flight, per-accumulator FMA order unchanged => bit-identical.
// ---------------------------------------------------------------------------
__global__ __launch_bounds__(256) void chunk_attn(
    const float* __restrict__ qkv, const float* __restrict__ cbuf,
    const float* __restrict__ lnk_w, const float* __restrict__ lnk_b,
    const float* __restrict__ lnv_w, const float* __restrict__ lnv_b,
    _Float16* __restrict__ atth, _Float16* __restrict__ attl) {
  int blk = blockIdx.x;
  int c = blk % NCH;
  int bh = blk / NCH;
  int h = bh % Hh, b = bh / Hh;
  __shared__ float Qs[64][68];   // [d][n]
  __shared__ float Ks[64][68];   // [d][m]; later reused as Ps[m][n]
  __shared__ float Vs[64][68];   // [m][e]
  __shared__ float Ss[64][68];   // [d][e]
  __shared__ float kcs[64];
  __shared__ float rs[64][17];
  __shared__ float denomS[64];
  float (*Ps)[68] = Ks;          // overlay

  int tid = threadIdx.x;
  int tx = tid & 15, ty = tid >> 4;
  const float* base = qkv + (size_t)(b * Nn + c * CH) * TQKV + h * Dd;
  for (int i = tid; i < CH * 16; i += 256) {
    int row = i >> 4, c4 = i & 15;
    float4 fq = *(const float4*)(base + (size_t)row * TQKV + c4 * 4);
    Qs[c4 * 4 + 0][row] = fq.x; Qs[c4 * 4 + 1][row] = fq.y;
    Qs[c4 * 4 + 2][row] = fq.z; Qs[c4 * 4 + 3][row] = fq.w;
    float4 fk = *(const float4*)(base + (size_t)row * TQKV + INNER + c4 * 4);
    Ks[c4 * 4 + 0][row] = fk.x; Ks[c4 * 4 + 1][row] = fk.y;
    Ks[c4 * 4 + 2][row] = fk.z; Ks[c4 * 4 + 3][row] = fk.w;
    float4 fv = *(const float4*)(base + (size_t)row * TQKV + 2 * INNER + c4 * 4);
    *(float4*)&Vs[row][c4 * 4] = fv;
  }
  const float* sp = cbuf + (size_t)blk * CSZ;
  for (int i = tid; i < 1024; i += 256) {
    int row = i >> 4;
    *(float4*)&Ss[row][(i & 15) * 4] = *(const float4*)(sp + (size_t)i * 4);
  }
  if (tid < 16) {
    float4 f = *(const float4*)(sp + Dd * Dd + tid * 4);
    kcs[tid * 4 + 0] = f.x; kcs[tid * 4 + 1] = f.y;
    kcs[tid * 4 + 2] = f.z; kcs[tid * 4 + 3] = f.w;
  }
  __syncthreads();

  // --- LN recompute (bit-identical to chunk_sums_ln's LN) ---
  if (tid < 64) {
    int m = tid;
    float s = 0.f, s2 = 0.f;
#pragma unroll
    for (int j = 0; j < 64; j += 4) {
      float a0 = Ks[j + 0][m], a1 = Ks[j + 1][m];
      float a2 = Ks[j + 2][m], a3 = Ks[j + 3][m];
      s += a0 + a1 + a2 + a3;
      s2 += a0 * a0 + a1 * a1 + a2 * a2 + a3 * a3;
    }
    float mean = s * (1.f / 64.f);
    float var = s2 * (1.f / 64.f) - mean * mean;
    float inv = 1.0f / sqrtf(var + EPSF);
#pragma unroll
    for (int j = 0; j < 64; ++j)
      Ks[j][m] = (Ks[j][m] - mean) * inv * lnk_w[h * Dd + j] + lnk_b[h * Dd + j];
  } else if (tid < 128) {
    int row = tid & 63;
    float* R = &Vs[row][0];
    float s = 0.f, s2 = 0.f;
#pragma unroll
    for (int j = 0; j < 64; j += 4) {
      float4 v = *(const float4*)&R[j];
      s += v.x + v.y + v.z + v.w;
      s2 += v.x * v.x + v.y * v.y + v.z * v.z + v.w * v.w;
    }
    float mean = s * (1.f / 64.f);
    float var = s2 * (1.f / 64.f) - mean * mean;
    float inv = 1.0f / sqrtf(var + EPSF);
#pragma unroll
    for (int j = 0; j < 64; ++j)
      R[j] = (R[j] - mean) * inv * lnv_w[h * Dd + j] + lnv_b[h * Dd + j];
  }
  __syncthreads();

  // P = Q K^T into registers
  float accP[4][4] = {};
#pragma unroll 8
  for (int kk = 0; kk < 64; ++kk) {
    float4 qa = *(const float4*)&Qs[kk][ty * 4];
    float4 kb = *(const float4*)&Ks[kk][tx * 4];
    float qv[4] = {qa.x, qa.y, qa.z, qa.w};
    float kv[4] = {kb.x, kb.y, kb.z, kb.w};
#pragma unroll
    for (int i = 0; i < 4; ++i)
#pragma unroll
      for (int j = 0; j < 4; ++j) accP[i][j] += qv[i] * kv[j];
  }
  __syncthreads();  // Ks reads done before Ps overlay is written

#pragma unroll
  for (int i = 0; i < 4; ++i) {
    int n = ty * 4 + i;
    float rsum = 0.f;
#pragma unroll
    for (int j = 0; j < 4; ++j) {
      int m = tx * 4 + j;
      float p = (m <= n) ? accP[i][j] : 0.f;
      Ps[m][n] = p;
      rsum += p;
    }
    rs[n][tx] = rsum;
  }
  __syncthreads();

  // O = Q * S_prefix; denom
  float accO[4][4] = {};
#pragma unroll 8
  for (int d = 0; d < 64; ++d) {
    float4 qa = *(const float4*)&Qs[d][ty * 4];
    float4 sb = *(const float4*)&Ss[d][tx * 4];
    float qv[4] = {qa.x, qa.y, qa.z, qa.w};
    float sv[4] = {sb.x, sb.y, sb.z, sb.w};
#pragma unroll
    for (int i = 0; i < 4; ++i)
#pragma unroll
      for (int j = 0; j < 4; ++j) accO[i][j] += qv[i] * sv[j];
  }
  if (tid < 64) {
    int n = tid;
    float qkc = 0.f, qs = 0.f;
#pragma unroll 8
    for (int d = 0; d < 64; ++d) {
      float q = Qs[d][n];
      qkc += q * kcs[d];
      qs += q;
    }
    float rsum = 0.f;
#pragma unroll
    for (int t2 = 0; t2 < 16; ++t2) rsum += rs[n][t2];
    denomS[n] = qkc + rsum + EPSF * qs;
  }
  __syncthreads();

  // O += P_masked * V
#pragma unroll 8
  for (int m = 0; m < 64; ++m) {
    float4 pa = *(const float4*)&Ps[m][ty * 4];
    float4 vb = *(const float4*)&Vs[m][tx * 4];
    float pv[4] = {pa.x, pa.y, pa.z, pa.w};
    float vv[4] = {vb.x, vb.y, vb.z, vb.w};
#pragma unroll
    for (int i = 0; i < 4; ++i)
#pragma unroll
      for (int j = 0; j < 4; ++j) accO[i][j] += pv[i] * vv[j];
  }

  size_t obase = (size_t)(b * Nn + c * CH) * INNER + h * Dd;
#pragma unroll
  for (int i = 0; i < 4; ++i) {
    int n = ty * 4 + i;
    float dinv = 1.0f / denomS[n];
    float scale = dinv * (1.0f / (float)Nn);
    half4 hv, lv;
#pragma unroll
    for (int j = 0; j < 4; ++j) {
      float o = accO[i][j] * scale;
      _Float16 hh = (_Float16)o;
      hv[j] = hh;
      lv[j] = (_Float16)((o - (float)hh) * 2048.0f);
    }
    *(half4*)(atth + obase + (size_t)n * INNER + tx * 4) = hv;
    *(half4*)(attl + obase + (size_t)n * INNER + tx * 4) = lv;
  }
}

// ---------------------------------------------------------------------------
extern "C" void kernel_launch(void* const* d_in, const int* in_sizes, int n_in,
                              void* d_out, int out_size, void* d_ws,
                              size_t ws_size, hipStream_t stream) {
  const float* x     = (const float*)d_in[0];
  const float* w_qkv = (const float*)d_in[1];
  const float* lnk_w = (const float*)d_in[2];
  const float* lnk_b = (const float*)d_in[3];
  const float* lnv_w = (const float*)d_in[4];
  const float* lnv_b = (const float*)d_in[5];
  const float* w_out = (const float*)d_in[6];
  const float* b_out = (const float*)d_in[7];
  float* out = (float*)d_out;

  // Workspace layout (~52.56 MB, the exact R0-proven layout):
  float* qkv  = (float*)d_ws;                      // 4096*1536 fp32
  float* cbuf = qkv + (size_t)Mm * TQKV;           // 512*4160 fp32
  _Float16* atth = (_Float16*)(cbuf + (size_t)Bb * Hh * NCH * CSZ);
  _Float16* attl = atth + (size_t)Mm * INNER;
  _Float16* woh  = attl + (size_t)Mm * INNER;
  _Float16* wol  = woh + (size_t)INNER * 512;
  _Float16* xh   = wol + (size_t)INNER * 512;      // x split 4096x512
  _Float16* xl   = xh + (size_t)Mm * 512;
  _Float16* wvh  = xl + (size_t)Mm * 512;          // w_qkv v-rows split 512x512
  _Float16* wvl  = wvh + (size_t)INNER * 512;

  // 1a. ONE split dispatch: x + w_qkv v-rows + w_out
  split_all<<<2560, 256, 0, stream>>>(
      x, w_qkv + (size_t)1024 * 512, w_out,
      xh, xl, wvh, wvl, woh, wol);

  // 1b. GEMM1-qk (fp32 VALU, N=1024): R0-exact (~70 us proven)
  gemm1_f32<<<dim3(1024 / 64, Mm / 128), 256, 0, stream>>>(x, w_qkv, qkv);

  // 1c. GEMM1-v (2-term split MFMA, N=512): writes qkv cols 1024..1535
  gemm_split_nt<<<dim3(512 / 64, Mm / 128), 256, 0, stream>>>(
      xh, xl, wvh, wvl, nullptr, qkv + 1024, TQKV, 512);

  // 2. LN(k,v) + per-chunk K^T V + colsum(K) — no qkv writeback
  chunk_sums_ln<<<Bb * Hh * NCH, 256, 0, stream>>>(
      qkv, lnk_w, lnk_b, lnv_w, lnv_b, cbuf);

  // 3. Exclusive prefix over chunks — batched loads/stores
  chunk_prefix<<<dim3((CSZ + 255) / 256, Bb * Hh), 256, 0, stream>>>(cbuf);

  // 4. Per-chunk attention (applies LN itself) -> attn split f16
  chunk_attn<<<Bb * Hh * NCH, 256, 0, stream>>>(
      qkv, cbuf, lnk_w, lnk_b, lnv_w, lnv_b, atth, attl);

  // 5. Output GEMM: out = attn * w_out^T + b_out (2-term split MFMA)
  gemm_split_nt<<<dim3(INNER / 64, Mm / 128), 256, 0, stream>>>(
      atth, attl, woh, wol, b_out, out, INNER, 512);
}